// Round 2
// 761.002 us; speedup vs baseline: 1.0508x; 1.0508x over previous
//
#include <hip/hip_runtime.h>
#include <stdint.h>

#define N_ROWS   2048
#define D_IN     1024
#define V_OUT    32000
#define SLEN_C   512
#define BATCH_C  32
#define CVOC     500
#define OUT_COLS 32500

#define MIN_NORM_F 1e-15f
#define PROJ_EPS_F 4e-3f

typedef __bf16 bf16x8_t __attribute__((ext_vector_type(8)));
typedef float  f32x4_t  __attribute__((ext_vector_type(4)));
typedef unsigned short ushort8_t __attribute__((ext_vector_type(8)));

__device__ __forceinline__ unsigned short f2bf(float f) {
    uint32_t b = __float_as_uint(f);
    b += 0x7FFFu + ((b >> 16) & 1u);           // round-to-nearest-even
    return (unsigned short)(b >> 16);
}
__device__ __forceinline__ float bf2f(unsigned short u) {
    return __uint_as_float(((uint32_t)u) << 16);
}
__device__ __forceinline__ float wave_sum(float v) {
#pragma unroll
    for (int off = 32; off > 0; off >>= 1) v += __shfl_down(v, off, 64);
    return v;
}

// async global->LDS, 16B per lane, wave-uniform LDS base
__device__ __forceinline__ void load_lds16(const void* g, void* l) {
    __builtin_amdgcn_global_load_lds(
        (const __attribute__((address_space(1))) void*)g,
        (__attribute__((address_space(3))) void*)l, 16, 0, 0);
}

// ---------------- fp32 -> bf16 cast (vectorized) ----------------
__global__ __launch_bounds__(256)
void cast_f32_to_bf16(const float* __restrict__ src, unsigned short* __restrict__ dst, int n4) {
    int i = blockIdx.x * blockDim.x + threadIdx.x;
    int stride = gridDim.x * blockDim.x;
    for (; i < n4; i += stride) {
        float4 v = ((const float4*)src)[i];
        ushort4 o;
        o.x = f2bf(v.x); o.y = f2bf(v.y); o.z = f2bf(v.z); o.w = f2bf(v.w);
        ((ushort4*)dst)[i] = o;
    }
}

// ---------------- per-row: g = artanh(min(||x||,1-1e-7))/||x||, p_copy ----------------
__global__ __launch_bounds__(256)
void row_stats(const float* __restrict__ hidden, const float* __restrict__ Wc,
               const float* __restrict__ bc_in, float* __restrict__ g_arr,
               float* __restrict__ pc_arr) {
    __shared__ float red[8];
    const int n = blockIdx.x;
    const int tid = threadIdx.x;
    float4 hv = *(const float4*)(hidden + (size_t)n * D_IN + tid * 4);
    float4 wv = *(const float4*)(Wc + tid * 4);
    float s = hv.x * hv.x + hv.y * hv.y + hv.z * hv.z + hv.w * hv.w;
    float d = hv.x * wv.x + hv.y * wv.y + hv.z * wv.z + hv.w * wv.w;
    s = wave_sum(s); d = wave_sum(d);
    const int w = tid >> 6, l = tid & 63;
    if (l == 0) { red[w] = s; red[4 + w] = d; }
    __syncthreads();
    if (tid == 0) {
        float S  = red[0] + red[1] + red[2] + red[3];
        float Dc = red[4] + red[5] + red[6] + red[7];
        float xn = fmaxf(sqrtf(S), MIN_NORM_F);
        float xc = fminf(xn, 1.f - 1e-7f);
        float at = 0.5f * logf((1.f + xc) / (1.f - xc));   // artanh
        float g = at / xn;
        float mxn = fmaxf(fabsf(Dc), MIN_NORM_F);
        float res = tanhf(mxn * g) * (Dc / mxn);
        float bcv = bc_in[0];
        float x2 = res * res, y2 = bcv * bcv, xyv = res * bcv;
        float num = (1.f + 2.f * xyv + y2) * res + (1.f - x2) * bcv;
        float dn  = fmaxf(1.f + 2.f * xyv + x2 * y2, MIN_NORM_F);
        float o = num / dn;
        float an = fmaxf(fabsf(o), MIN_NORM_F);
        float mxp = 1.f - PROJ_EPS_F;
        if (an > mxp) o = o / an * mxp;
        pc_arr[n] = 1.f / (1.f + expf(-o));
        g_arr[n]  = g;
    }
}

// ---------------- bf16 MFMA GEMM: Mx[n][v] = sum_k H[n][k]*W[v][k] ----------------
// 256x256 tile, BK=64, 8 waves (2Mx4N), 8-phase counted-vmcnt schedule
// (T1 XCD swizzle + T2 LDS XOR-swizzle + T3/T4 8-phase counted vmcnt + T5 setprio).
// LDS: 2 double-buffered K-tiles of A and B = 128 KiB, 1 block/CU.
// T2: linear global_load_lds dest + inverse-swizzled global source; ds_read
// applies byte ^= ((row&7)<<4) within each 128B row (rule #21: both sides).
// Stage schedule (per 8-phase iteration over K-tiles 2t/2t+1, staging 2t+1..2t+3):
//   ph1: B01->buf1(k1)  ph2: B23->buf1(k1)  ph3: A13->buf1(k1)
//   ph4: A02->buf0(k2), vmcnt(2)
//   ph5: B01->buf0(k2)  ph6: B23->buf0(k2)  ph7: A13->buf0(k2)+A02->buf1(k3)
//   ph8: vmcnt(2)
// Every staged region is barrier-separated from its last reader; vmcnt(2)
// leaves exactly the 2 newest (not-yet-needed) loads in flight.
// Output: bf16, written into the first 64000 B of each d_out row (aliased;
// epilogue caches whole row in LDS before overwriting with fp32 probs).

#define STG_A(bufi, chunk, kti) \
    load_lds16(Ag + (size_t)(am0 + ((chunk) << 6) + wave8 + srow) * D_IN + ((kti) << 6) + sk, \
               &Asmem[bufi][(((chunk) << 6) + wave8) << 6])
#define STG_B(bufi, chunk, kti) \
    load_lds16(Bg + (size_t)(bn0 + ((chunk) << 6) + wave8 + srow) * D_IN + ((kti) << 6) + sk, \
               &Bsmem[bufi][(((chunk) << 6) + wave8) << 6])

#define VMCNT(N) \
    __builtin_amdgcn_sched_barrier(0); \
    asm volatile("s_waitcnt vmcnt(" #N ")" ::: "memory"); \
    __builtin_amdgcn_sched_barrier(0);

#define RD_A(RB, MH) \
    _Pragma("unroll") for (int i = 0; i < 4; ++i) { \
        const int r_ = (wm + (MH)*64 + i*16 + fr) << 6; \
        af0[i] = *(const bf16x8_t*)&Asmem[RB][r_ + e0]; \
        af1[i] = *(const bf16x8_t*)&Asmem[RB][r_ + e1]; }

#define RD_B(RB, J0) \
    _Pragma("unroll") for (int j = 0; j < 2; ++j) { \
        const int r_ = (wn + ((J0) + j)*16 + fr) << 6; \
        bf0[(J0)+j] = *(const bf16x8_t*)&Bsmem[RB][r_ + e0]; \
        bf1[(J0)+j] = *(const bf16x8_t*)&Bsmem[RB][r_ + e1]; }

#define MM(MH, J0) \
    __builtin_amdgcn_sched_barrier(0); \
    __builtin_amdgcn_s_barrier(); \
    asm volatile("s_waitcnt lgkmcnt(0)" ::: "memory"); \
    __builtin_amdgcn_sched_barrier(0); \
    __builtin_amdgcn_s_setprio(1); \
    _Pragma("unroll") for (int i = 0; i < 4; ++i) \
        _Pragma("unroll") for (int j = 0; j < 2; ++j) { \
            acc[(MH)*4+i][(J0)+j] = __builtin_amdgcn_mfma_f32_16x16x32_bf16(af0[i], bf0[(J0)+j], acc[(MH)*4+i][(J0)+j], 0, 0, 0); \
            acc[(MH)*4+i][(J0)+j] = __builtin_amdgcn_mfma_f32_16x16x32_bf16(af1[i], bf1[(J0)+j], acc[(MH)*4+i][(J0)+j], 0, 0, 0); } \
    __builtin_amdgcn_s_setprio(0); \
    __builtin_amdgcn_s_barrier(); \
    __builtin_amdgcn_sched_barrier(0);

__global__ __launch_bounds__(512, 2)
void gemm_bt_bf16(const unsigned short* __restrict__ Ag,   // hidden bf16 [2048][1024]
                  const unsigned short* __restrict__ Bg,   // W bf16 [32000][1024]
                  unsigned short* __restrict__ Cb)         // bf16 rows, stride OUT_COLS*2
{
    __shared__ __align__(16) unsigned short Asmem[2][256 * 64];
    __shared__ __align__(16) unsigned short Bsmem[2][256 * 64];
    const int tid  = threadIdx.x;
    const int wave = tid >> 6;
    const int lane = tid & 63;

    // T1: bijective XCD swizzle; 1000 blocks = 8 XCDs x 125, m-tile fastest
    const int f   = blockIdx.x;
    const int swz = (f & 7) * 125 + (f >> 3);
    const int am0 = (swz & 7) * 256;      // 8 m-tiles
    const int bn0 = (swz >> 3) * 256;     // 125 n-tiles

    const int wr = wave >> 2, wc = wave & 3;
    const int wm = wr * 128, wn = wc * 64;      // wave output sub-tile origin
    const int fr  = lane & 15;                  // fragment row
    const int fkb = (lane >> 4) << 4;           // fragment k byte offset {0,16,32,48}
    const int swzr = (fr & 7) << 4;             // T2 swizzle term
    const int e0 = (fkb ^ swzr) >> 1;           // element offsets (kk=0 / kk=32)
    const int e1 = ((64 + fkb) ^ swzr) >> 1;
    const int wave8 = wave << 3;
    const int srow  = lane >> 3;                // staging row-in-8 (== row&7)
    const int sk    = ((lane & 7) ^ srow) << 3; // inverse-swizzled source k offset

    f32x4_t acc[8][4] = {};
    bf16x8_t af0[4], af1[4], bf0[4], bf1[4];

    // prologue: tile 0 -> buf0 (all 8 chunks), tile 1 -> buf1 (A chunks 0,2)
    STG_A(0, 0, 0); STG_A(0, 1, 0); STG_A(0, 2, 0); STG_A(0, 3, 0);
    STG_B(0, 0, 0); STG_B(0, 1, 0); STG_B(0, 2, 0); STG_B(0, 3, 0);
    STG_A(1, 0, 1); STG_A(1, 2, 1);
    VMCNT(2)
    __builtin_amdgcn_s_barrier();

    for (int t = 0; t < 7; ++t) {
        const int k1 = 2 * t + 1, k2 = 2 * t + 2, k3 = 2 * t + 3;
        // ---- K-tile 2t from buf0 ----
        RD_A(0, 0); RD_B(0, 0); STG_B(1, 0, k1); STG_B(1, 1, k1); MM(0, 0);
        RD_B(0, 2);             STG_B(1, 2, k1); STG_B(1, 3, k1); MM(0, 2);
        RD_A(0, 1);             STG_A(1, 1, k1); STG_A(1, 3, k1); MM(1, 0);
        STG_A(0, 0, k2); STG_A(0, 2, k2);
        VMCNT(2)                                                  MM(1, 2);
        // ---- K-tile 2t+1 from buf1 ----
        RD_A(1, 0); RD_B(1, 0); STG_B(0, 0, k2); STG_B(0, 1, k2); MM(0, 0);
        RD_B(1, 2);             STG_B(0, 2, k2); STG_B(0, 3, k2); MM(0, 2);
        RD_A(1, 1);             STG_A(0, 1, k2); STG_A(0, 3, k2);
                                STG_A(1, 0, k3); STG_A(1, 2, k3); MM(1, 0);
        VMCNT(2)                                                  MM(1, 2);
    }
    // ---- tail: K-tiles 14 (buf0) and 15 (buf1); buf1 already has A02(15) ----
    RD_A(0, 0); RD_B(0, 0); STG_B(1, 0, 15); STG_B(1, 1, 15); MM(0, 0);
    RD_B(0, 2);             STG_B(1, 2, 15); STG_B(1, 3, 15); MM(0, 2);
    RD_A(0, 1);             STG_A(1, 1, 15); STG_A(1, 3, 15); MM(1, 0);
    VMCNT(0)                                                  MM(1, 2);
    RD_A(1, 0); RD_B(1, 0); MM(0, 0);
    RD_B(1, 2);             MM(0, 2);
    RD_A(1, 1);             MM(1, 0);
                            MM(1, 2);

    // C/D layout: col = lane&15, row = (lane>>4)*4 + reg
    const int cm = (lane >> 4) << 2;
    const int cn = lane & 15;
#pragma unroll
    for (int I = 0; I < 8; ++I) {
#pragma unroll
        for (int J = 0; J < 4; ++J) {
            const int mg = am0 + wm + I * 16 + cm;
            const int ng = bn0 + wn + J * 16 + cn;
            unsigned short* cp = Cb + (size_t)mg * (OUT_COLS * 2) + ng;
#pragma unroll
            for (int r = 0; r < 4; ++r)
                cp[(size_t)r * (OUT_COLS * 2)] = f2bf(acc[I][J][r]);
        }
    }
}

// ---------------- fused mobius_add + project + softmax epilogue ----------------
// Reads bf16 Mx row (aliased at start of its own d_out row), caches in LDS,
// computes per-row P,Q (incl. Sb = sum b^2 folded into pass 1), exp once
// (bf16 back into LDS, pad zeroed), then scales + writes fp32 probs in-place.
__global__ __launch_bounds__(1024)
void softmax_epi(float* __restrict__ Cout, const float* __restrict__ bvec,
                 const float* __restrict__ g_arr, const float* __restrict__ pc_arr,
                 const int* __restrict__ pad_ptr) {
    __shared__ unsigned short mxls[V_OUT];   // bf16 row cache, 64000 B
    __shared__ float red[48];
    __shared__ float bcast[4];
    const int n = blockIdx.x;
    const int tid = threadIdx.x;
    float* row = Cout + (size_t)n * OUT_COLS;
    const unsigned short* rowb = (const unsigned short*)row;   // bf16 Mx alias
    const int pad = *pad_ptr;

    float s1 = 0.f, s2 = 0.f, s3 = 0.f;
    for (int i = tid * 8; i < V_OUT; i += 8192) {
        ushort8_t mu = *(const ushort8_t*)(rowb + i);
        float4 b0 = *(const float4*)(bvec + i);
        float4 b1 = *(const float4*)(bvec + i + 4);
        float m0 = bf2f(mu[0]), m1 = bf2f(mu[1]), m2 = bf2f(mu[2]), m3 = bf2f(mu[3]);
        float m4 = bf2f(mu[4]), m5 = bf2f(mu[5]), m6 = bf2f(mu[6]), m7 = bf2f(mu[7]);
        s1 += (m0*m0 + m1*m1 + m2*m2 + m3*m3) + (m4*m4 + m5*m5 + m6*m6 + m7*m7);
        s2 += (m0*b0.x + m1*b0.y + m2*b0.z + m3*b0.w) + (m4*b1.x + m5*b1.y + m6*b1.z + m7*b1.w);
        s3 += (b0.x*b0.x + b0.y*b0.y + b0.z*b0.z + b0.w*b0.w)
            + (b1.x*b1.x + b1.y*b1.y + b1.z*b1.z + b1.w*b1.w);
        *(ushort8_t*)&mxls[i] = mu;
    }
    s1 = wave_sum(s1); s2 = wave_sum(s2); s3 = wave_sum(s3);
    const int w = tid >> 6, l = tid & 63;
    if (l == 0) { red[w] = s1; red[16 + w] = s2; red[32 + w] = s3; }
    __syncthreads();
    if (tid == 0) {
        float S1 = 0.f, S2 = 0.f, Sb = 0.f;
        for (int k = 0; k < 16; ++k) { S1 += red[k]; S2 += red[16 + k]; Sb += red[32 + k]; }
        const float g  = g_arr[n];
        const float r   = fmaxf(sqrtf(S1), MIN_NORM_F);
        const float t   = tanhf(r * g);
        const float smv = t / r;                 // mobius_matvec scale
        const float x2 = smv * smv * S1;
        const float xy = smv * S2;
        const float den = fmaxf(1.f + 2.f * xy + x2 * Sb, MIN_NORM_F);
        float P = (1.f + 2.f * xy + Sb) * smv / den;
        float Q = (1.f - x2) / den;
        const float nrm = fmaxf(sqrtf(P * P * S1 + 2.f * P * Q * S2 + Q * Q * Sb), MIN_NORM_F);
        const float mxp = 1.f - PROJ_EPS_F;
        if (nrm > mxp) { const float fsc = mxp / nrm; P *= fsc; Q *= fsc; }
        bcast[0] = P; bcast[1] = Q;
    }
    __syncthreads();
    const float P = bcast[0], Q = bcast[1];

    // pass 2: exp once, store bf16 exp back into LDS, zero the pad slot
    float z = 0.f;
    for (int i = tid * 8; i < V_OUT; i += 8192) {
        ushort8_t mu = *(const ushort8_t*)&mxls[i];
        float4 b0 = *(const float4*)(bvec + i);
        float4 b1 = *(const float4*)(bvec + i + 4);
        float e0 = __expf(fmaf(P, bf2f(mu[0]), Q * b0.x));
        float e1 = __expf(fmaf(P, bf2f(mu[1]), Q * b0.y));
        float e2 = __expf(fmaf(P, bf2f(mu[2]), Q * b0.z));
        float e3 = __expf(fmaf(P, bf2f(mu[3]), Q * b0.w));
        float e4 = __expf(fmaf(P, bf2f(mu[4]), Q * b1.x));
        float e5 = __expf(fmaf(P, bf2f(mu[5]), Q * b1.y));
        float e6 = __expf(fmaf(P, bf2f(mu[6]), Q * b1.z));
        float e7 = __expf(fmaf(P, bf2f(mu[7]), Q * b1.w));
        if (i + 0 == pad) e0 = 0.f;
        if (i + 1 == pad) e1 = 0.f;
        if (i + 2 == pad) e2 = 0.f;
        if (i + 3 == pad) e3 = 0.f;
        if (i + 4 == pad) e4 = 0.f;
        if (i + 5 == pad) e5 = 0.f;
        if (i + 6 == pad) e6 = 0.f;
        if (i + 7 == pad) e7 = 0.f;
        z += ((e0 + e1) + (e2 + e3)) + ((e4 + e5) + (e6 + e7));
        ushort8_t eu;
        eu[0] = f2bf(e0); eu[1] = f2bf(e1); eu[2] = f2bf(e2); eu[3] = f2bf(e3);
        eu[4] = f2bf(e4); eu[5] = f2bf(e5); eu[6] = f2bf(e6); eu[7] = f2bf(e7);
        *(ushort8_t*)&mxls[i] = eu;
    }
    z = wave_sum(z);
    if (l == 0) red[w] = z;
    __syncthreads();
    if (tid == 0) {
        float a = 0.f;
        for (int k = 0; k < 16; ++k) a += red[k];
        bcast[2] = a;
    }
    __syncthreads();
    const float scale = (1.f - pc_arr[n]) / bcast[2];

    // pass 3: scale + write fp32 (overwrites the bf16 alias region; all reads done)
    for (int i = tid * 8; i < V_OUT; i += 8192) {
        ushort8_t eu = *(const ushort8_t*)&mxls[i];
        float4 o0, o1;
        o0.x = bf2f(eu[0]) * scale; o0.y = bf2f(eu[1]) * scale;
        o0.z = bf2f(eu[2]) * scale; o0.w = bf2f(eu[3]) * scale;
        o1.x = bf2f(eu[4]) * scale; o1.y = bf2f(eu[5]) * scale;
        o1.z = bf2f(eu[6]) * scale; o1.w = bf2f(eu[7]) * scale;
        *(float4*)(row + i) = o0;
        *(float4*)(row + i + 4) = o1;
    }
}

// ---------------- copy path: out[t*32+b][32000+c] = pc * sum_s attn[t*32+b][s]*src[s][b][c] ----
__global__ __launch_bounds__(128)
void copy_einsum(const float* __restrict__ attn, const float* __restrict__ src_map,
                 const float* __restrict__ pc_arr, float* __restrict__ Cout) {
    __shared__ float atile[32][128];
    const int tid = threadIdx.x;
    const int cc = blockIdx.x;        // 0..3  (c chunk of 128)
    const int b  = blockIdx.y;        // 0..31
    const int t0 = blockIdx.z * 32;   // 0 or 32
    const int c = cc * 128 + tid;
    const bool cv = (c < CVOC);

    float acc[32];
#pragma unroll
    for (int t = 0; t < 32; ++t) acc[t] = 0.f;

    for (int s0 = 0; s0 < SLEN_C; s0 += 128) {
        __syncthreads();
        for (int idx = tid; idx < 32 * 128; idx += 128) {
            const int t = idx >> 7, s = idx & 127;
            atile[t][s] = attn[(size_t)((t0 + t) * BATCH_C + b) * SLEN_C + s0 + s];
        }
        __syncthreads();
        for (int j = 0; j < 128; j += 4) {
            float sv0 = 0.f, sv1 = 0.f, sv2 = 0.f, sv3 = 0.f;
            if (cv) {
                const float* sp = src_map + (size_t)(s0 + j) * (BATCH_C * CVOC) + b * CVOC + c;
                sv0 = sp[0];
                sv1 = sp[BATCH_C * CVOC];
                sv2 = sp[2 * BATCH_C * CVOC];
                sv3 = sp[3 * BATCH_C * CVOC];
            }
#pragma unroll
            for (int t = 0; t < 32; ++t) {
                const float4 av = *(const float4*)&atile[t][j];
                acc[t] = fmaf(av.x, sv0, acc[t]);
                acc[t] = fmaf(av.y, sv1, acc[t]);
                acc[t] = fmaf(av.z, sv2, acc[t]);
                acc[t] = fmaf(av.w, sv3, acc[t]);
            }
        }
    }
    if (cv) {
#pragma unroll
        for (int t = 0; t < 32; ++t) {
            const int n = (t0 + t) * BATCH_C + b;
            Cout[(size_t)n * OUT_COLS + V_OUT + c] = acc[t] * pc_arr[n];
        }
    }
}

extern "C" void kernel_launch(void* const* d_in, const int* in_sizes, int n_in,
                              void* d_out, int out_size, void* d_ws, size_t ws_size,
                              hipStream_t stream) {
    const float* hidden  = (const float*)d_in[0];
    const float* attn    = (const float*)d_in[1];
    const float* src_map = (const float*)d_in[2];
    const float* W       = (const float*)d_in[3];
    const float* bvec    = (const float*)d_in[4];
    const float* Wc      = (const float*)d_in[5];
    const float* bc      = (const float*)d_in[6];
    const int*   padp    = (const int*)d_in[7];
    float* out = (float*)d_out;

    const int wb_elems = V_OUT * D_IN;    // 32,768,000
    const int hb_elems = N_ROWS * D_IN;   //  2,097,152
    unsigned short* Wb = (unsigned short*)d_ws;
    unsigned short* Hb = Wb + wb_elems;
    float* g_arr  = (float*)(Hb + hb_elems);
    float* pc_arr = g_arr + N_ROWS;
    // ws bytes used: 65,536,000 + 4,194,304 + 2*8192 ~= 69.8 MB

    cast_f32_to_bf16<<<4000, 256, 0, stream>>>(W, Wb, wb_elems / 4);
    cast_f32_to_bf16<<<512, 256, 0, stream>>>(hidden, Hb, hb_elems / 4);
    row_stats<<<N_ROWS, 256, 0, stream>>>(hidden, Wc, bc, g_arr, pc_arr);

    gemm_bt_bf16<<<1000, 512, 0, stream>>>(Hb, Wb, (unsigned short*)out);

    softmax_epi<<<N_ROWS, 1024, 0, stream>>>(out, bvec, g_arr, pc_arr, padp);

    dim3 egrid(4, BATCH_C, 2);
    copy_einsum<<<egrid, 128, 0, stream>>>(attn, src_map, pc_arr, out);
}

// Round 3
// 732.642 us; speedup vs baseline: 1.0914x; 1.0387x over previous
//
#include <hip/hip_runtime.h>
#include <stdint.h>

#define N_ROWS   2048
#define D_IN     1024
#define V_OUT    32000
#define SLEN_C   512
#define BATCH_C  32
#define CVOC     500
#define OUT_COLS 32500

#define MIN_NORM_F 1e-15f
#define PROJ_EPS_F 4e-3f

typedef __bf16 bf16x8_t __attribute__((ext_vector_type(8)));
typedef float  f32x4_t  __attribute__((ext_vector_type(4)));
typedef unsigned short ushort8_t __attribute__((ext_vector_type(8)));

__device__ __forceinline__ unsigned short f2bf(float f) {
    uint32_t b = __float_as_uint(f);
    b += 0x7FFFu + ((b >> 16) & 1u);           // round-to-nearest-even
    return (unsigned short)(b >> 16);
}
__device__ __forceinline__ float bf2f(unsigned short u) {
    return __uint_as_float(((uint32_t)u) << 16);
}
__device__ __forceinline__ float wave_sum(float v) {
#pragma unroll
    for (int off = 32; off > 0; off >>= 1) v += __shfl_down(v, off, 64);
    return v;
}

// async global->LDS, 16B per lane, wave-uniform LDS base
__device__ __forceinline__ void load_lds16(const void* g, void* l) {
    __builtin_amdgcn_global_load_lds(
        (const __attribute__((address_space(1))) void*)g,
        (__attribute__((address_space(3))) void*)l, 16, 0, 0);
}

// ---------------- fp32 -> bf16 cast (vectorized) ----------------
__global__ __launch_bounds__(256)
void cast_f32_to_bf16(const float* __restrict__ src, unsigned short* __restrict__ dst, int n4) {
    int i = blockIdx.x * blockDim.x + threadIdx.x;
    int stride = gridDim.x * blockDim.x;
    for (; i < n4; i += stride) {
        float4 v = ((const float4*)src)[i];
        ushort4 o;
        o.x = f2bf(v.x); o.y = f2bf(v.y); o.z = f2bf(v.z); o.w = f2bf(v.w);
        ((ushort4*)dst)[i] = o;
    }
}

// ---------------- per-row: g = artanh(min(||x||,1-1e-7))/||x||, p_copy ----------------
__global__ __launch_bounds__(256)
void row_stats(const float* __restrict__ hidden, const float* __restrict__ Wc,
               const float* __restrict__ bc_in, float* __restrict__ g_arr,
               float* __restrict__ pc_arr) {
    __shared__ float red[8];
    const int n = blockIdx.x;
    const int tid = threadIdx.x;
    float4 hv = *(const float4*)(hidden + (size_t)n * D_IN + tid * 4);
    float4 wv = *(const float4*)(Wc + tid * 4);
    float s = hv.x * hv.x + hv.y * hv.y + hv.z * hv.z + hv.w * hv.w;
    float d = hv.x * wv.x + hv.y * wv.y + hv.z * wv.z + hv.w * wv.w;
    s = wave_sum(s); d = wave_sum(d);
    const int w = tid >> 6, l = tid & 63;
    if (l == 0) { red[w] = s; red[4 + w] = d; }
    __syncthreads();
    if (tid == 0) {
        float S  = red[0] + red[1] + red[2] + red[3];
        float Dc = red[4] + red[5] + red[6] + red[7];
        float xn = fmaxf(sqrtf(S), MIN_NORM_F);
        float xc = fminf(xn, 1.f - 1e-7f);
        float at = 0.5f * logf((1.f + xc) / (1.f - xc));   // artanh
        float g = at / xn;
        float mxn = fmaxf(fabsf(Dc), MIN_NORM_F);
        float res = tanhf(mxn * g) * (Dc / mxn);
        float bcv = bc_in[0];
        float x2 = res * res, y2 = bcv * bcv, xyv = res * bcv;
        float num = (1.f + 2.f * xyv + y2) * res + (1.f - x2) * bcv;
        float dn  = fmaxf(1.f + 2.f * xyv + x2 * y2, MIN_NORM_F);
        float o = num / dn;
        float an = fmaxf(fabsf(o), MIN_NORM_F);
        float mxp = 1.f - PROJ_EPS_F;
        if (an > mxp) o = o / an * mxp;
        pc_arr[n] = 1.f / (1.f + expf(-o));
        g_arr[n]  = g;
    }
}

// ---------------- bf16 MFMA GEMM: Mx[n][v] = sum_k H[n][k]*W[v][k] ----------------
// 256x256 tile, BK=64, 8 waves (2Mx4N), 8-phase schedule with DERIVED waits:
// earliest-safe staging gives each fence 3 phases of lead, vmcnt(6) leaves
// exactly the 6 younger (not-yet-needed) loads in flight (m201/m218 T4).
// Per-chunk last-read phases (sealed by that phase's exit barrier):
//   buf0: A02 ph1, B ph2, A13 ph3;  buf1: A02 ph5, B ph6, A13 ph7.
// Steady-state stage slots (iter consumes T0=2t buf0 ph1-4, T1=2t+1 buf1 ph5-8):
//   ph1: A13(T1)->buf1   ph2: A02(T2)->buf0  ph3: B01(T2)->buf0
//   ph4: B23(T2)->buf0, vmcnt(6)  [youngest needed: A13(T1)@ph1, lead 3]
//   ph5: A13(T2)->buf0   ph6: A02(T3)->buf1  ph7: B01(T3)->buf1
//   ph8: B23(T3)->buf1, vmcnt(6)  [youngest needed: A13(T2)@ph5, lead 3]
// T2 swizzle: linear global_load_lds dest + inverse-swizzled global source;
// ds_read applies byte ^= ((row&7)<<4) (rule #21: both sides).
// Output: bf16, written into the first 64000 B of each d_out row (aliased;
// epilogue caches whole row in LDS before overwriting with fp32 probs).

#define STG_A(bufi, chunk, kti) \
    load_lds16(Ag + (size_t)(am0 + ((chunk) << 6) + wave8 + srow) * D_IN + ((kti) << 6) + sk, \
               &Asmem[bufi][(((chunk) << 6) + wave8) << 6])
#define STG_B(bufi, chunk, kti) \
    load_lds16(Bg + (size_t)(bn0 + ((chunk) << 6) + wave8 + srow) * D_IN + ((kti) << 6) + sk, \
               &Bsmem[bufi][(((chunk) << 6) + wave8) << 6])

#define VMCNT(N) \
    __builtin_amdgcn_sched_barrier(0); \
    asm volatile("s_waitcnt vmcnt(" #N ")" ::: "memory"); \
    __builtin_amdgcn_sched_barrier(0);

#define RD_A(RB, MH) \
    _Pragma("unroll") for (int i = 0; i < 4; ++i) { \
        const int r_ = (wm + (MH)*64 + i*16 + fr) << 6; \
        af0[i] = *(const bf16x8_t*)&Asmem[RB][r_ + e0]; \
        af1[i] = *(const bf16x8_t*)&Asmem[RB][r_ + e1]; }

#define RD_B(RB, J0) \
    _Pragma("unroll") for (int j = 0; j < 2; ++j) { \
        const int r_ = (wn + ((J0) + j)*16 + fr) << 6; \
        bf0[(J0)+j] = *(const bf16x8_t*)&Bsmem[RB][r_ + e0]; \
        bf1[(J0)+j] = *(const bf16x8_t*)&Bsmem[RB][r_ + e1]; }

#define MM(MH, J0) \
    __builtin_amdgcn_sched_barrier(0); \
    __builtin_amdgcn_s_barrier(); \
    asm volatile("s_waitcnt lgkmcnt(0)" ::: "memory"); \
    __builtin_amdgcn_sched_barrier(0); \
    __builtin_amdgcn_s_setprio(1); \
    _Pragma("unroll") for (int i = 0; i < 4; ++i) \
        _Pragma("unroll") for (int j = 0; j < 2; ++j) { \
            acc[(MH)*4+i][(J0)+j] = __builtin_amdgcn_mfma_f32_16x16x32_bf16(af0[i], bf0[(J0)+j], acc[(MH)*4+i][(J0)+j], 0, 0, 0); \
            acc[(MH)*4+i][(J0)+j] = __builtin_amdgcn_mfma_f32_16x16x32_bf16(af1[i], bf1[(J0)+j], acc[(MH)*4+i][(J0)+j], 0, 0, 0); } \
    __builtin_amdgcn_s_setprio(0); \
    __builtin_amdgcn_s_barrier(); \
    __builtin_amdgcn_sched_barrier(0);

__global__ __launch_bounds__(512, 2)
void gemm_bt_bf16(const unsigned short* __restrict__ Ag,   // hidden bf16 [2048][1024]
                  const unsigned short* __restrict__ Bg,   // W bf16 [32000][1024]
                  unsigned short* __restrict__ Cb)         // bf16 rows, stride OUT_COLS*2
{
    __shared__ __align__(16) unsigned short Asmem[2][256 * 64];
    __shared__ __align__(16) unsigned short Bsmem[2][256 * 64];
    const int tid  = threadIdx.x;
    const int wave = tid >> 6;
    const int lane = tid & 63;

    // T1: bijective XCD swizzle; 1000 blocks = 8 XCDs x 125, m-tile fastest
    const int f   = blockIdx.x;
    const int swz = (f & 7) * 125 + (f >> 3);
    const int am0 = (swz & 7) * 256;      // 8 m-tiles
    const int bn0 = (swz >> 3) * 256;     // 125 n-tiles

    const int wr = wave >> 2, wc = wave & 3;
    const int wm = wr * 128, wn = wc * 64;      // wave output sub-tile origin
    const int fr  = lane & 15;                  // fragment row
    const int fkb = (lane >> 4) << 4;           // fragment k byte offset {0,16,32,48}
    const int swzr = (fr & 7) << 4;             // T2 swizzle term
    const int e0 = (fkb ^ swzr) >> 1;           // element offsets (kk=0 / kk=32)
    const int e1 = ((64 + fkb) ^ swzr) >> 1;
    const int wave8 = wave << 3;
    const int srow  = lane >> 3;                // staging row-in-8 (== row&7)
    const int sk    = ((lane & 7) ^ srow) << 3; // inverse-swizzled source k offset

    f32x4_t acc[8][4] = {};
    bf16x8_t af0[4], af1[4], bf0[4], bf1[4];

    // prologue: tile 0 full -> buf0 (8 loads first), then tile 1 minus A13 -> buf1 (6)
    STG_A(0, 0, 0); STG_A(0, 2, 0); STG_B(0, 0, 0); STG_B(0, 1, 0);
    STG_B(0, 2, 0); STG_B(0, 3, 0); STG_A(0, 1, 0); STG_A(0, 3, 0);
    STG_A(1, 0, 1); STG_A(1, 2, 1); STG_B(1, 0, 1); STG_B(1, 1, 1);
    STG_B(1, 2, 1); STG_B(1, 3, 1);
    VMCNT(6)
    __builtin_amdgcn_s_barrier();

    for (int t = 0; t < 7; ++t) {
        const int T1 = 2 * t + 1, T2 = 2 * t + 2, T3 = 2 * t + 3;
        // ---- K-tile 2t from buf0 ----
        RD_A(0, 0); RD_B(0, 0); STG_A(1, 1, T1); STG_A(1, 3, T1); MM(0, 0);
        RD_B(0, 2);             STG_A(0, 0, T2); STG_A(0, 2, T2); MM(0, 2);
        RD_A(0, 1);             STG_B(0, 0, T2); STG_B(0, 1, T2); MM(1, 0);
                                STG_B(0, 2, T2); STG_B(0, 3, T2);
        VMCNT(6)                                                  MM(1, 2);
        // ---- K-tile 2t+1 from buf1 ----
        RD_A(1, 0); RD_B(1, 0); STG_A(0, 1, T2); STG_A(0, 3, T2); MM(0, 0);
        RD_B(1, 2);             STG_A(1, 0, T3); STG_A(1, 2, T3); MM(0, 2);
        RD_A(1, 1);             STG_B(1, 0, T3); STG_B(1, 1, T3); MM(1, 0);
                                STG_B(1, 2, T3); STG_B(1, 3, T3);
        VMCNT(6)                                                  MM(1, 2);
    }
    // ---- tail: K-tiles 14 (buf0) and 15 (buf1); buf1 missing only A13(15) ----
    RD_A(0, 0); RD_B(0, 0); STG_A(1, 1, 15); STG_A(1, 3, 15); MM(0, 0);
    RD_B(0, 2);                                               MM(0, 2);
    RD_A(0, 1);                                               MM(1, 0);
    VMCNT(0)                                                  MM(1, 2);
    RD_A(1, 0); RD_B(1, 0); MM(0, 0);
    RD_B(1, 2);             MM(0, 2);
    RD_A(1, 1);             MM(1, 0);
                            MM(1, 2);

    // C/D layout: col = lane&15, row = (lane>>4)*4 + reg
    const int cm = (lane >> 4) << 2;
    const int cn = lane & 15;
#pragma unroll
    for (int I = 0; I < 8; ++I) {
#pragma unroll
        for (int J = 0; J < 4; ++J) {
            const int mg = am0 + wm + I * 16 + cm;
            const int ng = bn0 + wn + J * 16 + cn;
            unsigned short* cp = Cb + (size_t)mg * (OUT_COLS * 2) + ng;
#pragma unroll
            for (int r = 0; r < 4; ++r)
                cp[(size_t)r * (OUT_COLS * 2)] = f2bf(acc[I][J][r]);
        }
    }
}

// ---------------- fused mobius_add + project + softmax epilogue ----------------
// Reads bf16 Mx row (aliased at start of its own d_out row), caches in LDS,
// computes per-row P,Q (incl. Sb = sum b^2 folded into pass 1), exp once
// (bf16 back into LDS, pad zeroed), then scales + writes fp32 probs in-place.
__global__ __launch_bounds__(1024)
void softmax_epi(float* __restrict__ Cout, const float* __restrict__ bvec,
                 const float* __restrict__ g_arr, const float* __restrict__ pc_arr,
                 const int* __restrict__ pad_ptr) {
    __shared__ unsigned short mxls[V_OUT];   // bf16 row cache, 64000 B
    __shared__ float red[48];
    __shared__ float bcast[4];
    const int n = blockIdx.x;
    const int tid = threadIdx.x;
    float* row = Cout + (size_t)n * OUT_COLS;
    const unsigned short* rowb = (const unsigned short*)row;   // bf16 Mx alias
    const int pad = *pad_ptr;

    float s1 = 0.f, s2 = 0.f, s3 = 0.f;
    for (int i = tid * 8; i < V_OUT; i += 8192) {
        ushort8_t mu = *(const ushort8_t*)(rowb + i);
        float4 b0 = *(const float4*)(bvec + i);
        float4 b1 = *(const float4*)(bvec + i + 4);
        float m0 = bf2f(mu[0]), m1 = bf2f(mu[1]), m2 = bf2f(mu[2]), m3 = bf2f(mu[3]);
        float m4 = bf2f(mu[4]), m5 = bf2f(mu[5]), m6 = bf2f(mu[6]), m7 = bf2f(mu[7]);
        s1 += (m0*m0 + m1*m1 + m2*m2 + m3*m3) + (m4*m4 + m5*m5 + m6*m6 + m7*m7);
        s2 += (m0*b0.x + m1*b0.y + m2*b0.z + m3*b0.w) + (m4*b1.x + m5*b1.y + m6*b1.z + m7*b1.w);
        s3 += (b0.x*b0.x + b0.y*b0.y + b0.z*b0.z + b0.w*b0.w)
            + (b1.x*b1.x + b1.y*b1.y + b1.z*b1.z + b1.w*b1.w);
        *(ushort8_t*)&mxls[i] = mu;
    }
    s1 = wave_sum(s1); s2 = wave_sum(s2); s3 = wave_sum(s3);
    const int w = tid >> 6, l = tid & 63;
    if (l == 0) { red[w] = s1; red[16 + w] = s2; red[32 + w] = s3; }
    __syncthreads();
    if (tid == 0) {
        float S1 = 0.f, S2 = 0.f, Sb = 0.f;
        for (int k = 0; k < 16; ++k) { S1 += red[k]; S2 += red[16 + k]; Sb += red[32 + k]; }
        const float g  = g_arr[n];
        const float r   = fmaxf(sqrtf(S1), MIN_NORM_F);
        const float t   = tanhf(r * g);
        const float smv = t / r;                 // mobius_matvec scale
        const float x2 = smv * smv * S1;
        const float xy = smv * S2;
        const float den = fmaxf(1.f + 2.f * xy + x2 * Sb, MIN_NORM_F);
        float P = (1.f + 2.f * xy + Sb) * smv / den;
        float Q = (1.f - x2) / den;
        const float nrm = fmaxf(sqrtf(P * P * S1 + 2.f * P * Q * S2 + Q * Q * Sb), MIN_NORM_F);
        const float mxp = 1.f - PROJ_EPS_F;
        if (nrm > mxp) { const float fsc = mxp / nrm; P *= fsc; Q *= fsc; }
        bcast[0] = P; bcast[1] = Q;
    }
    __syncthreads();
    const float P = bcast[0], Q = bcast[1];

    // pass 2: exp once, store bf16 exp back into LDS, zero the pad slot
    float z = 0.f;
    for (int i = tid * 8; i < V_OUT; i += 8192) {
        ushort8_t mu = *(const ushort8_t*)&mxls[i];
        float4 b0 = *(const float4*)(bvec + i);
        float4 b1 = *(const float4*)(bvec + i + 4);
        float e0 = __expf(fmaf(P, bf2f(mu[0]), Q * b0.x));
        float e1 = __expf(fmaf(P, bf2f(mu[1]), Q * b0.y));
        float e2 = __expf(fmaf(P, bf2f(mu[2]), Q * b0.z));
        float e3 = __expf(fmaf(P, bf2f(mu[3]), Q * b0.w));
        float e4 = __expf(fmaf(P, bf2f(mu[4]), Q * b1.x));
        float e5 = __expf(fmaf(P, bf2f(mu[5]), Q * b1.y));
        float e6 = __expf(fmaf(P, bf2f(mu[6]), Q * b1.z));
        float e7 = __expf(fmaf(P, bf2f(mu[7]), Q * b1.w));
        if (i + 0 == pad) e0 = 0.f;
        if (i + 1 == pad) e1 = 0.f;
        if (i + 2 == pad) e2 = 0.f;
        if (i + 3 == pad) e3 = 0.f;
        if (i + 4 == pad) e4 = 0.f;
        if (i + 5 == pad) e5 = 0.f;
        if (i + 6 == pad) e6 = 0.f;
        if (i + 7 == pad) e7 = 0.f;
        z += ((e0 + e1) + (e2 + e3)) + ((e4 + e5) + (e6 + e7));
        ushort8_t eu;
        eu[0] = f2bf(e0); eu[1] = f2bf(e1); eu[2] = f2bf(e2); eu[3] = f2bf(e3);
        eu[4] = f2bf(e4); eu[5] = f2bf(e5); eu[6] = f2bf(e6); eu[7] = f2bf(e7);
        *(ushort8_t*)&mxls[i] = eu;
    }
    z = wave_sum(z);
    if (l == 0) red[w] = z;
    __syncthreads();
    if (tid == 0) {
        float a = 0.f;
        for (int k = 0; k < 16; ++k) a += red[k];
        bcast[2] = a;
    }
    __syncthreads();
    const float scale = (1.f - pc_arr[n]) / bcast[2];

    // pass 3: scale + write fp32 (overwrites the bf16 alias region; all reads done)
    for (int i = tid * 8; i < V_OUT; i += 8192) {
        ushort8_t eu = *(const ushort8_t*)&mxls[i];
        float4 o0, o1;
        o0.x = bf2f(eu[0]) * scale; o0.y = bf2f(eu[1]) * scale;
        o0.z = bf2f(eu[2]) * scale; o0.w = bf2f(eu[3]) * scale;
        o1.x = bf2f(eu[4]) * scale; o1.y = bf2f(eu[5]) * scale;
        o1.z = bf2f(eu[6]) * scale; o1.w = bf2f(eu[7]) * scale;
        *(float4*)(row + i) = o0;
        *(float4*)(row + i + 4) = o1;
    }
}

// ---------------- copy path: out[t*32+b][32000+c] = pc * sum_s attn[t*32+b][s]*src[s][b][c] ----
__global__ __launch_bounds__(128)
void copy_einsum(const float* __restrict__ attn, const float* __restrict__ src_map,
                 const float* __restrict__ pc_arr, float* __restrict__ Cout) {
    __shared__ float atile[32][128];
    const int tid = threadIdx.x;
    const int cc = blockIdx.x;        // 0..3  (c chunk of 128)
    const int b  = blockIdx.y;        // 0..31
    const int t0 = blockIdx.z * 32;   // 0 or 32
    const int c = cc * 128 + tid;
    const bool cv = (c < CVOC);

    float acc[32];
#pragma unroll
    for (int t = 0; t < 32; ++t) acc[t] = 0.f;

    for (int s0 = 0; s0 < SLEN_C; s0 += 128) {
        __syncthreads();
        for (int idx = tid; idx < 32 * 128; idx += 128) {
            const int t = idx >> 7, s = idx & 127;
            atile[t][s] = attn[(size_t)((t0 + t) * BATCH_C + b) * SLEN_C + s0 + s];
        }
        __syncthreads();
        for (int j = 0; j < 128; j += 4) {
            float sv0 = 0.f, sv1 = 0.f, sv2 = 0.f, sv3 = 0.f;
            if (cv) {
                const float* sp = src_map + (size_t)(s0 + j) * (BATCH_C * CVOC) + b * CVOC + c;
                sv0 = sp[0];
                sv1 = sp[BATCH_C * CVOC];
                sv2 = sp[2 * BATCH_C * CVOC];
                sv3 = sp[3 * BATCH_C * CVOC];
            }
#pragma unroll
            for (int t = 0; t < 32; ++t) {
                const float4 av = *(const float4*)&atile[t][j];
                acc[t] = fmaf(av.x, sv0, acc[t]);
                acc[t] = fmaf(av.y, sv1, acc[t]);
                acc[t] = fmaf(av.z, sv2, acc[t]);
                acc[t] = fmaf(av.w, sv3, acc[t]);
            }
        }
    }
    if (cv) {
#pragma unroll
        for (int t = 0; t < 32; ++t) {
            const int n = (t0 + t) * BATCH_C + b;
            Cout[(size_t)n * OUT_COLS + V_OUT + c] = acc[t] * pc_arr[n];
        }
    }
}

extern "C" void kernel_launch(void* const* d_in, const int* in_sizes, int n_in,
                              void* d_out, int out_size, void* d_ws, size_t ws_size,
                              hipStream_t stream) {
    const float* hidden  = (const float*)d_in[0];
    const float* attn    = (const float*)d_in[1];
    const float* src_map = (const float*)d_in[2];
    const float* W       = (const float*)d_in[3];
    const float* bvec    = (const float*)d_in[4];
    const float* Wc      = (const float*)d_in[5];
    const float* bc      = (const float*)d_in[6];
    const int*   padp    = (const int*)d_in[7];
    float* out = (float*)d_out;

    const int wb_elems = V_OUT * D_IN;    // 32,768,000
    const int hb_elems = N_ROWS * D_IN;   //  2,097,152
    unsigned short* Wb = (unsigned short*)d_ws;
    unsigned short* Hb = Wb + wb_elems;
    float* g_arr  = (float*)(Hb + hb_elems);
    float* pc_arr = g_arr + N_ROWS;
    // ws bytes used: 65,536,000 + 4,194,304 + 2*8192 ~= 69.8 MB

    cast_f32_to_bf16<<<4000, 256, 0, stream>>>(W, Wb, wb_elems / 4);
    cast_f32_to_bf16<<<512, 256, 0, stream>>>(hidden, Hb, hb_elems / 4);
    row_stats<<<N_ROWS, 256, 0, stream>>>(hidden, Wc, bc, g_arr, pc_arr);

    gemm_bt_bf16<<<1000, 512, 0, stream>>>(Hb, Wb, (unsigned short*)out);

    softmax_epi<<<N_ROWS, 1024, 0, stream>>>(out, bvec, g_arr, pc_arr, padp);

    dim3 egrid(4, BATCH_C, 2);
    copy_einsum<<<egrid, 128, 0, stream>>>(attn, src_map, pc_arr, out);
}

// Round 4
// 727.533 us; speedup vs baseline: 1.0991x; 1.0070x over previous
//
#include <hip/hip_runtime.h>
#include <stdint.h>

#define N_ROWS   2048
#define D_IN     1024
#define V_OUT    32000
#define SLEN_C   512
#define BATCH_C  32
#define CVOC     500
#define OUT_COLS 32500

#define MIN_NORM_F 1e-15f
#define PROJ_EPS_F 4e-3f

typedef __bf16 bf16x8_t __attribute__((ext_vector_type(8)));
typedef float  f32x4_t  __attribute__((ext_vector_type(4)));
typedef unsigned short ushort8_t __attribute__((ext_vector_type(8)));

__device__ __forceinline__ unsigned short f2bf(float f) {
    uint32_t b = __float_as_uint(f);
    b += 0x7FFFu + ((b >> 16) & 1u);           // round-to-nearest-even
    return (unsigned short)(b >> 16);
}
__device__ __forceinline__ float bf2f(unsigned short u) {
    return __uint_as_float(((uint32_t)u) << 16);
}
__device__ __forceinline__ float wave_sum(float v) {
#pragma unroll
    for (int off = 32; off > 0; off >>= 1) v += __shfl_down(v, off, 64);
    return v;
}

// async global->LDS, 16B per lane, wave-uniform LDS base
__device__ __forceinline__ void load_lds16(const void* g, void* l) {
    __builtin_amdgcn_global_load_lds(
        (const __attribute__((address_space(1))) void*)g,
        (__attribute__((address_space(3))) void*)l, 16, 0, 0);
}

// ---------------- fp32 -> bf16 cast (vectorized) ----------------
__global__ __launch_bounds__(256)
void cast_f32_to_bf16(const float* __restrict__ src, unsigned short* __restrict__ dst, int n4) {
    int i = blockIdx.x * blockDim.x + threadIdx.x;
    int stride = gridDim.x * blockDim.x;
    for (; i < n4; i += stride) {
        float4 v = ((const float4*)src)[i];
        ushort4 o;
        o.x = f2bf(v.x); o.y = f2bf(v.y); o.z = f2bf(v.z); o.w = f2bf(v.w);
        ((ushort4*)dst)[i] = o;
    }
}

// ---------------- per-row: g = artanh(min(||x||,1-1e-7))/||x||, p_copy ----------------
__global__ __launch_bounds__(256)
void row_stats(const float* __restrict__ hidden, const float* __restrict__ Wc,
               const float* __restrict__ bc_in, float* __restrict__ g_arr,
               float* __restrict__ pc_arr) {
    __shared__ float red[8];
    const int n = blockIdx.x;
    const int tid = threadIdx.x;
    float4 hv = *(const float4*)(hidden + (size_t)n * D_IN + tid * 4);
    float4 wv = *(const float4*)(Wc + tid * 4);
    float s = hv.x * hv.x + hv.y * hv.y + hv.z * hv.z + hv.w * hv.w;
    float d = hv.x * wv.x + hv.y * wv.y + hv.z * wv.z + hv.w * wv.w;
    s = wave_sum(s); d = wave_sum(d);
    const int w = tid >> 6, l = tid & 63;
    if (l == 0) { red[w] = s; red[4 + w] = d; }
    __syncthreads();
    if (tid == 0) {
        float S  = red[0] + red[1] + red[2] + red[3];
        float Dc = red[4] + red[5] + red[6] + red[7];
        float xn = fmaxf(sqrtf(S), MIN_NORM_F);
        float xc = fminf(xn, 1.f - 1e-7f);
        float at = 0.5f * logf((1.f + xc) / (1.f - xc));   // artanh
        float g = at / xn;
        float mxn = fmaxf(fabsf(Dc), MIN_NORM_F);
        float res = tanhf(mxn * g) * (Dc / mxn);
        float bcv = bc_in[0];
        float x2 = res * res, y2 = bcv * bcv, xyv = res * bcv;
        float num = (1.f + 2.f * xyv + y2) * res + (1.f - x2) * bcv;
        float dn  = fmaxf(1.f + 2.f * xyv + x2 * y2, MIN_NORM_F);
        float o = num / dn;
        float an = fmaxf(fabsf(o), MIN_NORM_F);
        float mxp = 1.f - PROJ_EPS_F;
        if (an > mxp) o = o / an * mxp;
        pc_arr[n] = 1.f / (1.f + expf(-o));
        g_arr[n]  = g;
    }
}

// ---------------- bf16 MFMA GEMM: Mx[n][v] = sum_k H[n][k]*W[v][k] ----------------
// 256x256 tile, BK=64, 8 waves (2Mx4N), 8-phase schedule with DERIVED waits:
// earliest-safe staging gives each fence 3 phases of lead, vmcnt(6) leaves
// exactly the 6 younger (not-yet-needed) loads in flight (m201/m218 T4).
// Per-chunk last-read phases (sealed by that phase's exit barrier):
//   buf0: A02 ph1, B ph2, A13 ph3;  buf1: A02 ph5, B ph6, A13 ph7.
// Steady-state stage slots (iter consumes T0=2t buf0 ph1-4, T1=2t+1 buf1 ph5-8):
//   ph1: A13(T1)->buf1   ph2: A02(T2)->buf0  ph3: B01(T2)->buf0
//   ph4: B23(T2)->buf0, vmcnt(6)  [youngest needed: A13(T1)@ph1, lead 3]
//   ph5: A13(T2)->buf0   ph6: A02(T3)->buf1  ph7: B01(T3)->buf1
//   ph8: B23(T3)->buf1, vmcnt(6)  [youngest needed: A13(T2)@ph5, lead 3]
// T2 swizzle: linear global_load_lds dest + inverse-swizzled global source;
// ds_read applies byte ^= ((row&7)<<4) (rule #21: both sides).
// Epilogue: per-wave LDS transpose (private 16KB slice) -> row-linear wide
// stores (8 lanes cover a full 128B row-segment) -> write-amp 1.0.
// Output: bf16, written into the first 64000 B of each d_out row (aliased;
// epilogue kernel caches whole row in LDS before overwriting with fp32 probs).

#define STG_A(bufi, chunk, kti) \
    load_lds16(Ag + (size_t)(am0 + ((chunk) << 6) + wave8 + srow) * D_IN + ((kti) << 6) + sk, \
               &Asmem[bufi][(((chunk) << 6) + wave8) << 6])
#define STG_B(bufi, chunk, kti) \
    load_lds16(Bg + (size_t)(bn0 + ((chunk) << 6) + wave8 + srow) * D_IN + ((kti) << 6) + sk, \
               &Bsmem[bufi][(((chunk) << 6) + wave8) << 6])

#define VMCNT(N) \
    __builtin_amdgcn_sched_barrier(0); \
    asm volatile("s_waitcnt vmcnt(" #N ")" ::: "memory"); \
    __builtin_amdgcn_sched_barrier(0);

#define RD_A(RB, MH) \
    _Pragma("unroll") for (int i = 0; i < 4; ++i) { \
        const int r_ = (wm + (MH)*64 + i*16 + fr) << 6; \
        af0[i] = *(const bf16x8_t*)&Asmem[RB][r_ + e0]; \
        af1[i] = *(const bf16x8_t*)&Asmem[RB][r_ + e1]; }

#define RD_B(RB, J0) \
    _Pragma("unroll") for (int j = 0; j < 2; ++j) { \
        const int r_ = (wn + ((J0) + j)*16 + fr) << 6; \
        bf0[(J0)+j] = *(const bf16x8_t*)&Bsmem[RB][r_ + e0]; \
        bf1[(J0)+j] = *(const bf16x8_t*)&Bsmem[RB][r_ + e1]; }

#define MM(MH, J0) \
    __builtin_amdgcn_sched_barrier(0); \
    __builtin_amdgcn_s_barrier(); \
    asm volatile("s_waitcnt lgkmcnt(0)" ::: "memory"); \
    __builtin_amdgcn_sched_barrier(0); \
    __builtin_amdgcn_s_setprio(1); \
    _Pragma("unroll") for (int i = 0; i < 4; ++i) \
        _Pragma("unroll") for (int j = 0; j < 2; ++j) { \
            acc[(MH)*4+i][(J0)+j] = __builtin_amdgcn_mfma_f32_16x16x32_bf16(af0[i], bf0[(J0)+j], acc[(MH)*4+i][(J0)+j], 0, 0, 0); \
            acc[(MH)*4+i][(J0)+j] = __builtin_amdgcn_mfma_f32_16x16x32_bf16(af1[i], bf1[(J0)+j], acc[(MH)*4+i][(J0)+j], 0, 0, 0); } \
    __builtin_amdgcn_s_setprio(0); \
    __builtin_amdgcn_s_barrier(); \
    __builtin_amdgcn_sched_barrier(0);

__global__ __launch_bounds__(512, 2)
void gemm_bt_bf16(const unsigned short* __restrict__ Ag,   // hidden bf16 [2048][1024]
                  const unsigned short* __restrict__ Bg,   // W bf16 [32000][1024]
                  unsigned short* __restrict__ Cb)         // bf16 rows, stride OUT_COLS*2
{
    __shared__ __align__(16) unsigned short Asmem[2][256 * 64];
    __shared__ __align__(16) unsigned short Bsmem[2][256 * 64];
    const int tid  = threadIdx.x;
    const int wave = tid >> 6;
    const int lane = tid & 63;

    // T1: bijective XCD swizzle; 1000 blocks = 8 XCDs x 125, m-tile fastest
    const int f   = blockIdx.x;
    const int swz = (f & 7) * 125 + (f >> 3);
    const int am0 = (swz & 7) * 256;      // 8 m-tiles
    const int bn0 = (swz >> 3) * 256;     // 125 n-tiles

    const int wr = wave >> 2, wc = wave & 3;
    const int wm = wr * 128, wn = wc * 64;      // wave output sub-tile origin
    const int fr  = lane & 15;                  // fragment row
    const int fkb = (lane >> 4) << 4;           // fragment k byte offset {0,16,32,48}
    const int swzr = (fr & 7) << 4;             // T2 swizzle term
    const int e0 = (fkb ^ swzr) >> 1;           // element offsets (kk=0 / kk=32)
    const int e1 = ((64 + fkb) ^ swzr) >> 1;
    const int wave8 = wave << 3;
    const int srow  = lane >> 3;                // staging row-in-8 (== row&7)
    const int sk    = ((lane & 7) ^ srow) << 3; // inverse-swizzled source k offset

    f32x4_t acc[8][4] = {};
    bf16x8_t af0[4], af1[4], bf0[4], bf1[4];

    // prologue: tile 0 full -> buf0 (8 loads first), then tile 1 minus A13 -> buf1 (6)
    STG_A(0, 0, 0); STG_A(0, 2, 0); STG_B(0, 0, 0); STG_B(0, 1, 0);
    STG_B(0, 2, 0); STG_B(0, 3, 0); STG_A(0, 1, 0); STG_A(0, 3, 0);
    STG_A(1, 0, 1); STG_A(1, 2, 1); STG_B(1, 0, 1); STG_B(1, 1, 1);
    STG_B(1, 2, 1); STG_B(1, 3, 1);
    VMCNT(6)
    __builtin_amdgcn_s_barrier();

    for (int t = 0; t < 7; ++t) {
        const int T1 = 2 * t + 1, T2 = 2 * t + 2, T3 = 2 * t + 3;
        // ---- K-tile 2t from buf0 ----
        RD_A(0, 0); RD_B(0, 0); STG_A(1, 1, T1); STG_A(1, 3, T1); MM(0, 0);
        RD_B(0, 2);             STG_A(0, 0, T2); STG_A(0, 2, T2); MM(0, 2);
        RD_A(0, 1);             STG_B(0, 0, T2); STG_B(0, 1, T2); MM(1, 0);
                                STG_B(0, 2, T2); STG_B(0, 3, T2);
        VMCNT(6)                                                  MM(1, 2);
        // ---- K-tile 2t+1 from buf1 ----
        RD_A(1, 0); RD_B(1, 0); STG_A(0, 1, T2); STG_A(0, 3, T2); MM(0, 0);
        RD_B(1, 2);             STG_A(1, 0, T3); STG_A(1, 2, T3); MM(0, 2);
        RD_A(1, 1);             STG_B(1, 0, T3); STG_B(1, 1, T3); MM(1, 0);
                                STG_B(1, 2, T3); STG_B(1, 3, T3);
        VMCNT(6)                                                  MM(1, 2);
    }
    // ---- tail: K-tiles 14 (buf0) and 15 (buf1); buf1 missing only A13(15) ----
    RD_A(0, 0); RD_B(0, 0); STG_A(1, 1, 15); STG_A(1, 3, 15); MM(0, 0);
    RD_B(0, 2);                                               MM(0, 2);
    RD_A(0, 1);                                               MM(1, 0);
    VMCNT(0)                                                  MM(1, 2);
    RD_A(1, 0); RD_B(1, 0); MM(0, 0);
    RD_B(1, 2);             MM(0, 2);
    RD_A(1, 1);             MM(1, 0);
                            MM(1, 2);

    // ---- epilogue: per-wave LDS transpose, then coalesced wide C stores ----
    // Last MM ended with s_barrier: all waves past their LDS reads; LDS dead.
    // Each wave uses a PRIVATE 16KB slice (no cross-wave sharing -> no sync).
    // C/D layout: col = lane&15, row = (lane>>4)*4 + reg.
    unsigned short* slice = (wave < 4) ? (&Asmem[0][0] + (wave << 13))
                                       : (&Bsmem[0][0] + ((wave - 4) << 13));
    const int cm = (lane >> 4) << 2;
    const int cn = lane & 15;
#pragma unroll
    for (int I = 0; I < 8; ++I) {
#pragma unroll
        for (int J = 0; J < 4; ++J) {
#pragma unroll
            for (int r = 0; r < 4; ++r) {
                const int rl  = I * 16 + cm + r;                 // local row 0..127
                const int byt = (rl << 7) + ((J * 16 + cn) << 1);
                *(unsigned short*)((char*)slice + (byt ^ ((rl & 7) << 4))) = f2bf(acc[I][J][r]);
            }
        }
    }
    asm volatile("s_waitcnt lgkmcnt(0)" ::: "memory");   // within-wave LDS RAW fence
    __builtin_amdgcn_sched_barrier(0);
    const int rl0 = lane >> 3;            // row base 0..7
    const int bo  = (lane & 7) << 4;      // byte offset within 128B row
#pragma unroll
    for (int it = 0; it < 16; ++it) {
        const int rl  = rl0 + it * 8;
        const int byt = (rl << 7) + bo;   // (rl&7) == rl0, constant per lane
        uint4 v = *(const uint4*)((const char*)slice + (byt ^ (rl0 << 4)));
        const int mg = am0 + wm + rl;
        char* gp = (char*)Cb + (size_t)mg * (OUT_COLS * 2) + ((size_t)(bn0 + wn) << 1) + bo;
        *(uint2*)gp       = make_uint2(v.x, v.y);   // 8B stores: odd rows are only
        *(uint2*)(gp + 8) = make_uint2(v.z, v.w);   // 8B-aligned (65000%16==8)
    }
}

// ---------------- fused mobius_add + project + softmax epilogue ----------------
// Reads bf16 Mx row (aliased at start of its own d_out row), caches in LDS,
// computes per-row P,Q (incl. Sb = sum b^2 folded into pass 1), exp once
// (bf16 back into LDS, pad zeroed), then scales + writes fp32 probs in-place.
__global__ __launch_bounds__(1024)
void softmax_epi(float* __restrict__ Cout, const float* __restrict__ bvec,
                 const float* __restrict__ g_arr, const float* __restrict__ pc_arr,
                 const int* __restrict__ pad_ptr) {
    __shared__ unsigned short mxls[V_OUT];   // bf16 row cache, 64000 B
    __shared__ float red[48];
    __shared__ float bcast[4];
    const int n = blockIdx.x;
    const int tid = threadIdx.x;
    float* row = Cout + (size_t)n * OUT_COLS;
    const unsigned short* rowb = (const unsigned short*)row;   // bf16 Mx alias
    const int pad = *pad_ptr;

    float s1 = 0.f, s2 = 0.f, s3 = 0.f;
    for (int i = tid * 8; i < V_OUT; i += 8192) {
        ushort8_t mu = *(const ushort8_t*)(rowb + i);
        float4 b0 = *(const float4*)(bvec + i);
        float4 b1 = *(const float4*)(bvec + i + 4);
        float m0 = bf2f(mu[0]), m1 = bf2f(mu[1]), m2 = bf2f(mu[2]), m3 = bf2f(mu[3]);
        float m4 = bf2f(mu[4]), m5 = bf2f(mu[5]), m6 = bf2f(mu[6]), m7 = bf2f(mu[7]);
        s1 += (m0*m0 + m1*m1 + m2*m2 + m3*m3) + (m4*m4 + m5*m5 + m6*m6 + m7*m7);
        s2 += (m0*b0.x + m1*b0.y + m2*b0.z + m3*b0.w) + (m4*b1.x + m5*b1.y + m6*b1.z + m7*b1.w);
        s3 += (b0.x*b0.x + b0.y*b0.y + b0.z*b0.z + b0.w*b0.w)
            + (b1.x*b1.x + b1.y*b1.y + b1.z*b1.z + b1.w*b1.w);
        *(ushort8_t*)&mxls[i] = mu;
    }
    s1 = wave_sum(s1); s2 = wave_sum(s2); s3 = wave_sum(s3);
    const int w = tid >> 6, l = tid & 63;
    if (l == 0) { red[w] = s1; red[16 + w] = s2; red[32 + w] = s3; }
    __syncthreads();
    if (tid == 0) {
        float S1 = 0.f, S2 = 0.f, Sb = 0.f;
        for (int k = 0; k < 16; ++k) { S1 += red[k]; S2 += red[16 + k]; Sb += red[32 + k]; }
        const float g  = g_arr[n];
        const float r   = fmaxf(sqrtf(S1), MIN_NORM_F);
        const float t   = tanhf(r * g);
        const float smv = t / r;                 // mobius_matvec scale
        const float x2 = smv * smv * S1;
        const float xy = smv * S2;
        const float den = fmaxf(1.f + 2.f * xy + x2 * Sb, MIN_NORM_F);
        float P = (1.f + 2.f * xy + Sb) * smv / den;
        float Q = (1.f - x2) / den;
        const float nrm = fmaxf(sqrtf(P * P * S1 + 2.f * P * Q * S2 + Q * Q * Sb), MIN_NORM_F);
        const float mxp = 1.f - PROJ_EPS_F;
        if (nrm > mxp) { const float fsc = mxp / nrm; P *= fsc; Q *= fsc; }
        bcast[0] = P; bcast[1] = Q;
    }
    __syncthreads();
    const float P = bcast[0], Q = bcast[1];

    // pass 2: exp once, store bf16 exp back into LDS, zero the pad slot
    float z = 0.f;
    for (int i = tid * 8; i < V_OUT; i += 8192) {
        ushort8_t mu = *(const ushort8_t*)&mxls[i];
        float4 b0 = *(const float4*)(bvec + i);
        float4 b1 = *(const float4*)(bvec + i + 4);
        float e0 = __expf(fmaf(P, bf2f(mu[0]), Q * b0.x));
        float e1 = __expf(fmaf(P, bf2f(mu[1]), Q * b0.y));
        float e2 = __expf(fmaf(P, bf2f(mu[2]), Q * b0.z));
        float e3 = __expf(fmaf(P, bf2f(mu[3]), Q * b0.w));
        float e4 = __expf(fmaf(P, bf2f(mu[4]), Q * b1.x));
        float e5 = __expf(fmaf(P, bf2f(mu[5]), Q * b1.y));
        float e6 = __expf(fmaf(P, bf2f(mu[6]), Q * b1.z));
        float e7 = __expf(fmaf(P, bf2f(mu[7]), Q * b1.w));
        if (i + 0 == pad) e0 = 0.f;
        if (i + 1 == pad) e1 = 0.f;
        if (i + 2 == pad) e2 = 0.f;
        if (i + 3 == pad) e3 = 0.f;
        if (i + 4 == pad) e4 = 0.f;
        if (i + 5 == pad) e5 = 0.f;
        if (i + 6 == pad) e6 = 0.f;
        if (i + 7 == pad) e7 = 0.f;
        z += ((e0 + e1) + (e2 + e3)) + ((e4 + e5) + (e6 + e7));
        ushort8_t eu;
        eu[0] = f2bf(e0); eu[1] = f2bf(e1); eu[2] = f2bf(e2); eu[3] = f2bf(e3);
        eu[4] = f2bf(e4); eu[5] = f2bf(e5); eu[6] = f2bf(e6); eu[7] = f2bf(e7);
        *(ushort8_t*)&mxls[i] = eu;
    }
    z = wave_sum(z);
    if (l == 0) red[w] = z;
    __syncthreads();
    if (tid == 0) {
        float a = 0.f;
        for (int k = 0; k < 16; ++k) a += red[k];
        bcast[2] = a;
    }
    __syncthreads();
    const float scale = (1.f - pc_arr[n]) / bcast[2];

    // pass 3: scale + write fp32 (overwrites the bf16 alias region; all reads done)
    for (int i = tid * 8; i < V_OUT; i += 8192) {
        ushort8_t eu = *(const ushort8_t*)&mxls[i];
        float4 o0, o1;
        o0.x = bf2f(eu[0]) * scale; o0.y = bf2f(eu[1]) * scale;
        o0.z = bf2f(eu[2]) * scale; o0.w = bf2f(eu[3]) * scale;
        o1.x = bf2f(eu[4]) * scale; o1.y = bf2f(eu[5]) * scale;
        o1.z = bf2f(eu[6]) * scale; o1.w = bf2f(eu[7]) * scale;
        *(float4*)(row + i) = o0;
        *(float4*)(row + i + 4) = o1;
    }
}

// ---------------- copy path: out[t*32+b][32000+c] = pc * sum_s attn[t*32+b][s]*src[s][b][c] ----
__global__ __launch_bounds__(128)
void copy_einsum(const float* __restrict__ attn, const float* __restrict__ src_map,
                 const float* __restrict__ pc_arr, float* __restrict__ Cout) {
    __shared__ float atile[32][128];
    const int tid = threadIdx.x;
    const int cc = blockIdx.x;        // 0..3  (c chunk of 128)
    const int b  = blockIdx.y;        // 0..31
    const int t0 = blockIdx.z * 32;   // 0 or 32
    const int c = cc * 128 + tid;
    const bool cv = (c < CVOC);

    float acc[32];
#pragma unroll
    for (int t = 0; t < 32; ++t) acc[t] = 0.f;

    for (int s0 = 0; s0 < SLEN_C; s0 += 128) {
        __syncthreads();
        for (int idx = tid; idx < 32 * 128; idx += 128) {
            const int t = idx >> 7, s = idx & 127;
            atile[t][s] = attn[(size_t)((t0 + t) * BATCH_C + b) * SLEN_C + s0 + s];
        }
        __syncthreads();
        for (int j = 0; j < 128; j += 4) {
            float sv0 = 0.f, sv1 = 0.f, sv2 = 0.f, sv3 = 0.f;
            if (cv) {
                const float* sp = src_map + (size_t)(s0 + j) * (BATCH_C * CVOC) + b * CVOC + c;
                sv0 = sp[0];
                sv1 = sp[BATCH_C * CVOC];
                sv2 = sp[2 * BATCH_C * CVOC];
                sv3 = sp[3 * BATCH_C * CVOC];
            }
#pragma unroll
            for (int t = 0; t < 32; ++t) {
                const float4 av = *(const float4*)&atile[t][j];
                acc[t] = fmaf(av.x, sv0, acc[t]);
                acc[t] = fmaf(av.y, sv1, acc[t]);
                acc[t] = fmaf(av.z, sv2, acc[t]);
                acc[t] = fmaf(av.w, sv3, acc[t]);
            }
        }
    }
    if (cv) {
#pragma unroll
        for (int t = 0; t < 32; ++t) {
            const int n = (t0 + t) * BATCH_C + b;
            Cout[(size_t)n * OUT_COLS + V_OUT + c] = acc[t] * pc_arr[n];
        }
    }
}

extern "C" void kernel_launch(void* const* d_in, const int* in_sizes, int n_in,
                              void* d_out, int out_size, void* d_ws, size_t ws_size,
                              hipStream_t stream) {
    const float* hidden  = (const float*)d_in[0];
    const float* attn    = (const float*)d_in[1];
    const float* src_map = (const float*)d_in[2];
    const float* W       = (const float*)d_in[3];
    const float* bvec    = (const float*)d_in[4];
    const float* Wc      = (const float*)d_in[5];
    const float* bc      = (const float*)d_in[6];
    const int*   padp    = (const int*)d_in[7];
    float* out = (float*)d_out;

    const int wb_elems = V_OUT * D_IN;    // 32,768,000
    const int hb_elems = N_ROWS * D_IN;   //  2,097,152
    unsigned short* Wb = (unsigned short*)d_ws;
    unsigned short* Hb = Wb + wb_elems;
    float* g_arr  = (float*)(Hb + hb_elems);
    float* pc_arr = g_arr + N_ROWS;
    // ws bytes used: 65,536,000 + 4,194,304 + 2*8192 ~= 69.8 MB

    cast_f32_to_bf16<<<4000, 256, 0, stream>>>(W, Wb, wb_elems / 4);
    cast_f32_to_bf16<<<512, 256, 0, stream>>>(hidden, Hb, hb_elems / 4);
    row_stats<<<N_ROWS, 256, 0, stream>>>(hidden, Wc, bc, g_arr, pc_arr);

    gemm_bt_bf16<<<1000, 512, 0, stream>>>(Hb, Wb, (unsigned short*)out);

    softmax_epi<<<N_ROWS, 1024, 0, stream>>>(out, bvec, g_arr, pc_arr, padp);

    dim3 egrid(4, BATCH_C, 2);
    copy_einsum<<<egrid, 128, 0, stream>>>(attn, src_map, pc_arr, out);
}